// Round 5
// baseline (245.693 us; speedup 1.0000x reference)
//
#include <hip/hip_runtime.h>
#include <hip/hip_bf16.h>

#define NB   2
#define NH   16
#define NBH  (NB*NH)
#define SEQ  2048
#define DH   128

#define KBLK 64      // kv per tile
// legacy kernel params
#define QB   64
#define QW   16
#define KS   136
#define VS   72
#define PS   72

typedef short  short8    __attribute__((ext_vector_type(8)));
typedef short  short4v   __attribute__((ext_vector_type(4)));
typedef unsigned short ushort8_t __attribute__((ext_vector_type(8)));
typedef float  f32x4     __attribute__((ext_vector_type(4)));

constexpr float INV_T = 0.08838834764831845f;   // 1/sqrt(128)
constexpr float LOG2E = 1.4426950408889634f;
constexpr float QSCL  = INV_T * LOG2E;          // fold log2e into Q scale
constexpr float NEG   = -1e30f;
constexpr float DEFER = 8.0f;                   // defer-rescale threshold (log2 units)

__device__ __forceinline__ unsigned short f2b(float x) {
    union { float f; unsigned u; } c; c.f = x;
    unsigned r = c.u + 0x7FFFu + ((c.u >> 16) & 1u);
    return (unsigned short)(r >> 16);
}

__device__ __forceinline__ unsigned pack2(float lo, float hi) {
    return (unsigned)f2b(lo) | ((unsigned)f2b(hi) << 16);
}

__device__ __forceinline__ short4v mk4(unsigned lo, unsigned hi) {
    union { unsigned u[2]; short4v s; } x; x.u[0] = lo; x.u[1] = hi; return x.s;
}

// 16x16x16 bf16 MFMA: B-frag layout B[k=4*l4+j][col=l15] == native S^T C-layout,
// so P feeds PV straight from registers (no cross-lane movement).
__device__ __forceinline__ f32x4 mfma16(short4v a, short4v b, f32x4 c) {
#if __has_builtin(__builtin_amdgcn_mfma_f32_16x16x16bf16_1k)
    return __builtin_amdgcn_mfma_f32_16x16x16bf16_1k(a, b, c, 0, 0, 0);
#else
    f32x4 d;
    asm("v_mfma_f32_16x16x16_bf16 %0, %1, %2, %3"
        : "=v"(d) : "v"(a), "v"(b), "0"(c));
    return d;
#endif
}

__device__ __forceinline__ void gload_lds16(const void* g, void* l) {
    __builtin_amdgcn_global_load_lds(
        (const __attribute__((address_space(1))) unsigned int*)g,
        (__attribute__((address_space(3))) unsigned int*)l, 16, 0, 0);
}

// ---------------- prepass: K fp32 -> bf16 [bh][s][d] ----------------
__global__ __launch_bounds__(256)
void prep_k(const float* __restrict__ K, unsigned short* __restrict__ Kb) {
    size_t i = ((size_t)blockIdx.x * 256 + threadIdx.x) * 8;
    float4 a = *(const float4*)(K + i);
    float4 b = *(const float4*)(K + i + 4);
    ushort8_t o;
    o[0]=f2b(a.x); o[1]=f2b(a.y); o[2]=f2b(a.z); o[3]=f2b(a.w);
    o[4]=f2b(b.x); o[5]=f2b(b.y); o[6]=f2b(b.z); o[7]=f2b(b.w);
    *(ushort8_t*)(Kb + i) = o;
}

// ---------------- prepass: V fp32 [s][d] -> bf16 V^T [bh][d][s] ----------------
__global__ __launch_bounds__(256)
void prep_v(const float* __restrict__ V, unsigned short* __restrict__ Vt) {
    __shared__ unsigned short T[64][72];
    const int bid = blockIdx.x;
    const int dt = bid & 1, st = (bid >> 1) & 31, bh = bid >> 6;
    const int s0 = st * 64, d0 = dt * 64;
    const float* vb = V + (size_t)bh * SEQ * DH;
    const int tid = threadIdx.x;
    #pragma unroll
    for (int u = 0; u < 4; ++u) {
        int f = tid + 256 * u;
        int sl = f >> 4, c4 = f & 15;
        float4 x = *(const float4*)(vb + (size_t)(s0 + sl) * DH + d0 + c4 * 4);
        T[c4*4+0][sl] = f2b(x.x); T[c4*4+1][sl] = f2b(x.y);
        T[c4*4+2][sl] = f2b(x.z); T[c4*4+3][sl] = f2b(x.w);
    }
    __syncthreads();
    unsigned short* vo = Vt + (size_t)bh * DH * SEQ;
    const int dr = tid >> 2, ch = tid & 3;
    ushort8_t w0 = *(const ushort8_t*)&T[dr][ch*16];
    ushort8_t w1 = *(const ushort8_t*)&T[dr][ch*16 + 8];
    *(ushort8_t*)(vo + (size_t)(d0+dr)*SEQ + s0 + ch*16)     = w0;
    *(ushort8_t*)(vo + (size_t)(d0+dr)*SEQ + s0 + ch*16 + 8) = w1;
}

// ---------------- main: causal flash attention, 32 q-rows per wave ----------------
// Swapped QK^T (S^T = mfma(K,Q)): lane owns 2 q-rows (l15, l15+16), softmax fully
// in-register. Each K/V LDS read feeds both q-halfsets (halves LDS bytes/FLOP).
// PV uses 16x16x16 MFMA so P's native layout IS the B-fragment (no shuffles).
__global__ __launch_bounds__(256, 2)
void attn_fwd3(const float* __restrict__ Q,
               const unsigned short* __restrict__ Kb,
               const unsigned short* __restrict__ Vt,
               float* __restrict__ O)
{
    __shared__ __align__(16) unsigned short Ksh[2][64 * 128];
    __shared__ __align__(16) unsigned short Vsh[2][128 * 64];

    const int bid  = blockIdx.x;
    const int qblk = 15 - (bid >> 5);       // descending size: heavy blocks first
    const int bh   = bid & 31;
    const int tid  = threadIdx.x;
    const int wid  = tid >> 6;
    const int lane = tid & 63;
    const int l15  = lane & 15;
    const int l4   = lane >> 4;
    const int rx   = l15 & 7;               // row&7 for all fragment rows (16x+l15)

    const size_t base = (size_t)bh * SEQ * DH;
    const unsigned short* Kbh = Kb + base;        // [s][d]
    const unsigned short* Vth = Vt + base;        // [d][s]

    const int qbase = qblk * 128 + wid * 32;
    const int nt    = 2 * qblk + 2;
    const int qr0   = qbase + l15;
    const int qr1   = qbase + 16 + l15;

    auto stage = [&](int bufi, int tt) {
        const int kv0 = tt * KBLK;
        {   // K: 64 rows x 256B
            const int sl = lane & 15, rr = lane >> 4;
            #pragma unroll
            for (int i = 0; i < 4; ++i) {
                int row = wid * 16 + i * 4 + rr;
                int ss  = sl ^ (row & 7);
                gload_lds16(Kbh + (size_t)(kv0 + row) * DH + ss * 8,
                            &Ksh[bufi][(wid * 16 + i * 4) * 128]);
            }
        }
        {   // V^T: 128 rows x 128B
            const int sl = lane & 7, rr = lane >> 3;
            #pragma unroll
            for (int i = 0; i < 4; ++i) {
                int row = wid * 32 + i * 8 + rr;
                int ss  = sl ^ (row & 7);
                gload_lds16(Vth + (size_t)row * SEQ + kv0 + ss * 8,
                            &Vsh[bufi][(wid * 32 + i * 8) * 64]);
            }
        }
    };

    // ---- Q fragments (B-operand layout) for both q-halfsets, scaled ----
    short8 aq0[4], aq1[4];
    {
        const float* qp0 = Q + base + (size_t)qr0 * DH + 8 * l4;
        const float* qp1 = Q + base + (size_t)qr1 * DH + 8 * l4;
        #pragma unroll
        for (int kb = 0; kb < 4; ++kb) {
            float4 x0 = *(const float4*)(qp0 + 32 * kb);
            float4 x1 = *(const float4*)(qp0 + 32 * kb + 4);
            float4 y0 = *(const float4*)(qp1 + 32 * kb);
            float4 y1 = *(const float4*)(qp1 + 32 * kb + 4);
            short8 a, b;
            a[0] = (short)f2b(x0.x * QSCL); a[1] = (short)f2b(x0.y * QSCL);
            a[2] = (short)f2b(x0.z * QSCL); a[3] = (short)f2b(x0.w * QSCL);
            a[4] = (short)f2b(x1.x * QSCL); a[5] = (short)f2b(x1.y * QSCL);
            a[6] = (short)f2b(x1.z * QSCL); a[7] = (short)f2b(x1.w * QSCL);
            b[0] = (short)f2b(y0.x * QSCL); b[1] = (short)f2b(y0.y * QSCL);
            b[2] = (short)f2b(y0.z * QSCL); b[3] = (short)f2b(y0.w * QSCL);
            b[4] = (short)f2b(y1.x * QSCL); b[5] = (short)f2b(y1.y * QSCL);
            b[6] = (short)f2b(y1.z * QSCL); b[7] = (short)f2b(y1.w * QSCL);
            aq0[kb] = a; aq1[kb] = b;
        }
    }

    f32x4 acc0[8], acc1[8];     // O^T: acc{qs}[db][j] = O[qr{qs}][16db+4l4+j]
    #pragma unroll
    for (int i = 0; i < 8; ++i) {
        acc0[i] = (f32x4){0.f, 0.f, 0.f, 0.f};
        acc1[i] = (f32x4){0.f, 0.f, 0.f, 0.f};
    }
    float mrun0 = NEG, lrun0 = 0.f;
    float mrun1 = NEG, lrun1 = 0.f;

    stage(0, 0);

    for (int t = 0; t < nt; ++t) {
        const int cur = t & 1;
        const int kvb = t * KBLK;
        asm volatile("s_waitcnt vmcnt(0)" ::: "memory");
        __syncthreads();
        if (t + 1 < nt) stage(cur ^ 1, t + 1);

        if (kvb <= qbase + 31) {
            const unsigned short* Kc = Ksh[cur];
            const unsigned short* Vc = Vsh[cur];

            // ---- S^T = K · Q^T (64kv x 32q): each K b128 feeds both q-halves ----
            f32x4 sf0[4], sf1[4];
            __builtin_amdgcn_s_setprio(1);
            #pragma unroll
            for (int f = 0; f < 4; ++f) {
                f32x4 c0 = (f32x4){0.f, 0.f, 0.f, 0.f};
                f32x4 c1 = (f32x4){0.f, 0.f, 0.f, 0.f};
                const int row = 16 * f + l15;
                #pragma unroll
                for (int kb = 0; kb < 4; ++kb) {
                    short8 bk = *(const short8*)&Kc[row * 128 + ((4 * kb + l4) ^ rx) * 8];
                    c0 = __builtin_amdgcn_mfma_f32_16x16x32_bf16(bk, aq0[kb], c0, 0, 0, 0);
                    c1 = __builtin_amdgcn_mfma_f32_16x16x32_bf16(bk, aq1[kb], c1, 0, 0, 0);
                }
                sf0[f] = c0; sf1[f] = c1;
            }
            __builtin_amdgcn_s_setprio(0);

            // ---- causal mask (tiles overlapping the wave's diagonal) ----
            if (kvb + KBLK - 1 > qbase) {
                #pragma unroll
                for (int f = 0; f < 4; ++f) {
                    #pragma unroll
                    for (int j = 0; j < 4; ++j) {
                        const int kv = kvb + 16 * f + 4 * l4 + j;
                        if (kv > qr0) sf0[f][j] = NEG;
                        if (kv > qr1) sf1[f][j] = NEG;
                    }
                }
            }

            // ---- row max per halfset: local tree + 2 shfl_xor ----
            float pmax0, pmax1;
            {
                float a0 = fmaxf(fmaxf(sf0[0][0], sf0[0][1]), fmaxf(sf0[0][2], sf0[0][3]));
                float a1 = fmaxf(fmaxf(sf0[1][0], sf0[1][1]), fmaxf(sf0[1][2], sf0[1][3]));
                float a2 = fmaxf(fmaxf(sf0[2][0], sf0[2][1]), fmaxf(sf0[2][2], sf0[2][3]));
                float a3 = fmaxf(fmaxf(sf0[3][0], sf0[3][1]), fmaxf(sf0[3][2], sf0[3][3]));
                pmax0 = fmaxf(fmaxf(a0, a1), fmaxf(a2, a3));
                float b0 = fmaxf(fmaxf(sf1[0][0], sf1[0][1]), fmaxf(sf1[0][2], sf1[0][3]));
                float b1 = fmaxf(fmaxf(sf1[1][0], sf1[1][1]), fmaxf(sf1[1][2], sf1[1][3]));
                float b2 = fmaxf(fmaxf(sf1[2][0], sf1[2][1]), fmaxf(sf1[2][2], sf1[2][3]));
                float b3 = fmaxf(fmaxf(sf1[3][0], sf1[3][1]), fmaxf(sf1[3][2], sf1[3][3]));
                pmax1 = fmaxf(fmaxf(b0, b1), fmaxf(b2, b3));
            }
            pmax0 = fmaxf(pmax0, __shfl_xor(pmax0, 16));
            pmax0 = fmaxf(pmax0, __shfl_xor(pmax0, 32));
            pmax1 = fmaxf(pmax1, __shfl_xor(pmax1, 16));
            pmax1 = fmaxf(pmax1, __shfl_xor(pmax1, 32));

            // ---- defer-rescale (T13), combined wave-uniform trigger ----
            if (__any((pmax0 > mrun0 + DEFER) || (pmax1 > mrun1 + DEFER))) {
                float mn0 = fmaxf(mrun0, pmax0), mn1 = fmaxf(mrun1, pmax1);
                float s0 = exp2f(mrun0 - mn0),   s1 = exp2f(mrun1 - mn1);
                mrun0 = mn0; mrun1 = mn1;
                lrun0 *= s0; lrun1 *= s1;
                #pragma unroll
                for (int i = 0; i < 8; ++i)
                    #pragma unroll
                    for (int j = 0; j < 4; ++j) {
                        acc0[i][j] *= s0;
                        acc1[i][j] *= s1;
                    }
            }

            // ---- P = exp2(S - m), row sums, pack to bf16 dword pairs ----
            unsigned pa0[4], pb0_[4], pa1[4], pb1_[4];
            float rs0 = 0.f, rs1 = 0.f;
            #pragma unroll
            for (int f = 0; f < 4; ++f) {
                float p00 = exp2f(sf0[f][0] - mrun0), p01 = exp2f(sf0[f][1] - mrun0);
                float p02 = exp2f(sf0[f][2] - mrun0), p03 = exp2f(sf0[f][3] - mrun0);
                float p10 = exp2f(sf1[f][0] - mrun1), p11 = exp2f(sf1[f][1] - mrun1);
                float p12 = exp2f(sf1[f][2] - mrun1), p13 = exp2f(sf1[f][3] - mrun1);
                rs0 += (p00 + p01) + (p02 + p03);
                rs1 += (p10 + p11) + (p12 + p13);
                pa0[f]  = pack2(p00, p01); pb0_[f] = pack2(p02, p03);
                pa1[f]  = pack2(p10, p11); pb1_[f] = pack2(p12, p13);
            }
            rs0 += __shfl_xor(rs0, 16); rs0 += __shfl_xor(rs0, 32);
            rs1 += __shfl_xor(rs1, 16); rs1 += __shfl_xor(rs1, 32);
            lrun0 += rs0; lrun1 += rs1;

            // ---- PV: O^T += V^T · P via 16x16x16 (P native layout = B-frag) ----
            #pragma unroll
            for (int f = 0; f < 4; ++f) {
                short4v pf0 = mk4(pa0[f], pb0_[f]);
                short4v pf1 = mk4(pa1[f], pb1_[f]);
                __builtin_amdgcn_s_setprio(1);
                #pragma unroll
                for (int db = 0; db < 8; ++db) {
                    const int row = 16 * db + l15;
                    short4v va = *(const short4v*)
                        &Vc[row * 64 + ((2 * f + (l4 >> 1)) ^ rx) * 8 + (l4 & 1) * 4];
                    acc0[db] = mfma16(va, pf0, acc0[db]);
                    acc1[db] = mfma16(va, pf1, acc1[db]);
                }
                __builtin_amdgcn_s_setprio(0);
            }
        }
    }

    // ---- epilogue: O[qr][16db+4l4+j] = acc/l, float4 stores ----
    const float inv0 = 1.f / lrun0;
    const float inv1 = 1.f / lrun1;
    float* op0 = O + base + (size_t)qr0 * DH + 4 * l4;
    float* op1 = O + base + (size_t)qr1 * DH + 4 * l4;
    #pragma unroll
    for (int db = 0; db < 8; ++db) {
        float4 v0, v1;
        v0.x = acc0[db][0] * inv0; v0.y = acc0[db][1] * inv0;
        v0.z = acc0[db][2] * inv0; v0.w = acc0[db][3] * inv0;
        v1.x = acc1[db][0] * inv1; v1.y = acc1[db][1] * inv1;
        v1.z = acc1[db][2] * inv1; v1.w = acc1[db][3] * inv1;
        *(float4*)(op0 + 16 * db) = v0;
        *(float4*)(op1 + 16 * db) = v1;
    }
}

// ---------------- legacy fallback (round-1 kernel, used if ws too small) ----------------
__global__ __launch_bounds__(256)
void attn_fwd(const float* __restrict__ Q, const float* __restrict__ K,
              const float* __restrict__ V, float* __restrict__ O)
{
    __shared__ __align__(16) unsigned short KshL[KBLK * KS];
    __shared__ __align__(16) unsigned short VshL[DH * VS];
    __shared__ __align__(16) unsigned short PshL[4][QW * PS];

    const int bid  = blockIdx.x;
    const int qblk = bid & 31;
    const int bh   = bid >> 5;
    const int tid  = threadIdx.x;
    const int wid  = tid >> 6;
    const int lane = tid & 63;
    const int l15  = lane & 15;
    const int l4   = lane >> 4;

    const size_t base  = (size_t)bh * SEQ * DH;
    const int    qbase = qblk * QB + wid * QW;

    short8 aq[4];
    {
        const float* qp = Q + base + (size_t)(qbase + l15) * DH + 8 * l4;
        #pragma unroll
        for (int kb = 0; kb < 4; ++kb) {
            float4 x0 = *(const float4*)(qp + 32 * kb);
            float4 x1 = *(const float4*)(qp + 32 * kb + 4);
            short8 a;
            a[0] = (short)f2b(x0.x * INV_T); a[1] = (short)f2b(x0.y * INV_T);
            a[2] = (short)f2b(x0.z * INV_T); a[3] = (short)f2b(x0.w * INV_T);
            a[4] = (short)f2b(x1.x * INV_T); a[5] = (short)f2b(x1.y * INV_T);
            a[6] = (short)f2b(x1.z * INV_T); a[7] = (short)f2b(x1.w * INV_T);
            aq[kb] = a;
        }
    }
    f32x4 acc[8];
    #pragma unroll
    for (int i = 0; i < 8; ++i) acc[i] = (f32x4){0.f, 0.f, 0.f, 0.f};
    float mrun[4], lrun[4];
    #pragma unroll
    for (int j = 0; j < 4; ++j) { mrun[j] = NEG; lrun[j] = 0.f; }

    const int ntiles = qblk + 1;
    for (int t = 0; t < ntiles; ++t) {
        const int kvb = t * KBLK;
        #pragma unroll
        for (int i = 0; i < 8; ++i) {
            int f  = tid + 256 * i;
            int kv = f >> 5, c4 = f & 31;
            float4 x = *(const float4*)(K + base + (size_t)(kvb + kv) * DH + 4 * c4);
            ushort4 b4;
            b4.x = f2b(x.x); b4.y = f2b(x.y); b4.z = f2b(x.z); b4.w = f2b(x.w);
            *(ushort4*)&KshL[kv * KS + 4 * c4] = b4;
        }
        {
            const int dd  = tid & 127;
            const int kvg = (tid >> 7) * 8;
            #pragma unroll
            for (int p = 0; p < 4; ++p) {
                const int kvL = p * 16 + kvg;
                const float* vp = V + base + (size_t)(kvb + kvL) * DH + dd;
                float x[8];
                #pragma unroll
                for (int j = 0; j < 8; ++j) x[j] = vp[(size_t)j * DH];
                ushort4 lo, hi;
                lo.x = f2b(x[0]); lo.y = f2b(x[1]); lo.z = f2b(x[2]); lo.w = f2b(x[3]);
                hi.x = f2b(x[4]); hi.y = f2b(x[5]); hi.z = f2b(x[6]); hi.w = f2b(x[7]);
                *(ushort4*)&VshL[dd * VS + kvL]     = lo;
                *(ushort4*)&VshL[dd * VS + kvL + 4] = hi;
            }
        }
        __syncthreads();
        if (kvb <= qbase + QW - 1) {
            f32x4 sf[4];
            #pragma unroll
            for (int f = 0; f < 4; ++f) {
                f32x4 c = (f32x4){0.f, 0.f, 0.f, 0.f};
                #pragma unroll
                for (int kb = 0; kb < 4; ++kb) {
                    short8 bk = *(const short8*)&KshL[(16 * f + l15) * KS + 32 * kb + 8 * l4];
                    c = __builtin_amdgcn_mfma_f32_16x16x32_bf16(aq[kb], bk, c, 0, 0, 0);
                }
                sf[f] = c;
            }
            float pmax[4] = {NEG, NEG, NEG, NEG};
            #pragma unroll
            for (int f = 0; f < 4; ++f) {
                const int col = kvb + 16 * f + l15;
                #pragma unroll
                for (int j = 0; j < 4; ++j) {
                    const int row = qbase + 4 * l4 + j;
                    float val = (col <= row) ? sf[f][j] : NEG;
                    sf[f][j] = val;
                    pmax[j] = fmaxf(pmax[j], val);
                }
            }
            #pragma unroll
            for (int j = 0; j < 4; ++j) {
                #pragma unroll
                for (int off = 8; off > 0; off >>= 1)
                    pmax[j] = fmaxf(pmax[j], __shfl_xor(pmax[j], off));
            }
            float scl[4], rsum[4];
            #pragma unroll
            for (int j = 0; j < 4; ++j) {
                float mn = fmaxf(mrun[j], pmax[j]);
                scl[j]  = exp2f((mrun[j] - mn) * LOG2E);
                mrun[j] = mn;
                rsum[j] = 0.f;
            }
            #pragma unroll
            for (int f = 0; f < 4; ++f) {
                #pragma unroll
                for (int j = 0; j < 4; ++j) {
                    float pv = exp2f((sf[f][j] - mrun[j]) * LOG2E);
                    sf[f][j] = pv;
                    rsum[j] += pv;
                }
            }
            #pragma unroll
            for (int j = 0; j < 4; ++j) {
                #pragma unroll
                for (int off = 8; off > 0; off >>= 1)
                    rsum[j] += __shfl_xor(rsum[j], off);
                lrun[j] = lrun[j] * scl[j] + rsum[j];
            }
            #pragma unroll
            for (int i = 0; i < 8; ++i)
                #pragma unroll
                for (int j = 0; j < 4; ++j)
                    acc[i][j] *= scl[j];
            #pragma unroll
            for (int f = 0; f < 4; ++f)
                #pragma unroll
                for (int j = 0; j < 4; ++j)
                    PshL[wid][(4 * l4 + j) * PS + 16 * f + l15] = f2b(sf[f][j]);
            #pragma unroll
            for (int kb = 0; kb < 2; ++kb) {
                short8 pa = *(const short8*)&PshL[wid][l15 * PS + 32 * kb + 8 * l4];
                #pragma unroll
                for (int db = 0; db < 8; ++db) {
                    short8 bv = *(const short8*)&VshL[(16 * db + l15) * VS + 32 * kb + 8 * l4];
                    acc[db] = __builtin_amdgcn_mfma_f32_16x16x32_bf16(pa, bv, acc[db], 0, 0, 0);
                }
            }
        }
        __syncthreads();
    }
    float inv[4];
    #pragma unroll
    for (int j = 0; j < 4; ++j) inv[j] = 1.f / lrun[j];
    float* op = O + base + (size_t)qbase * DH;
    #pragma unroll
    for (int db = 0; db < 8; ++db)
        #pragma unroll
        for (int j = 0; j < 4; ++j)
            op[(size_t)(4 * l4 + j) * DH + 16 * db + l15] = acc[db][j] * inv[j];
}

extern "C" void kernel_launch(void* const* d_in, const int* in_sizes, int n_in,
                              void* d_out, int out_size, void* d_ws, size_t ws_size,
                              hipStream_t stream) {
    const float* q = (const float*)d_in[0];
    const float* k = (const float*)d_in[1];
    const float* v = (const float*)d_in[2];
    float* o = (float*)d_out;

    const size_t elems = (size_t)NBH * SEQ * DH;
    const size_t need  = elems * 2 * sizeof(unsigned short);   // Kbf + Vt, 33.5 MB
    if (ws_size >= need) {
        unsigned short* Kb = (unsigned short*)d_ws;
        unsigned short* Vt = Kb + elems;
        prep_k<<<dim3((unsigned)(elems / (256 * 8))), dim3(256), 0, stream>>>(k, Kb);
        prep_v<<<dim3(NBH * (SEQ / 64) * (DH / 64)), dim3(256), 0, stream>>>(v, Vt);
        attn_fwd3<<<dim3(NBH * 16), dim3(256), 0, stream>>>(q, Kb, Vt, o);
    } else {
        attn_fwd<<<dim3(NBH * 32), dim3(256), 0, stream>>>(q, k, v, o);
    }
}

// Round 7
// 245.470 us; speedup vs baseline: 1.0009x; 1.0009x over previous
//
#include <hip/hip_runtime.h>
#include <hip/hip_bf16.h>

#define NB   2
#define NH   16
#define NBH  (NB*NH)
#define SEQ  2048
#define DH   128

#define KBLK 64      // kv per tile
// legacy kernel params
#define QB   64
#define QW   16
#define KS   136
#define VS   72
#define PS   72

typedef short  short8    __attribute__((ext_vector_type(8)));
typedef short  short4v   __attribute__((ext_vector_type(4)));
typedef unsigned short ushort8_t __attribute__((ext_vector_type(8)));
typedef float  f32x4     __attribute__((ext_vector_type(4)));

constexpr float INV_T = 0.08838834764831845f;   // 1/sqrt(128)
constexpr float LOG2E = 1.4426950408889634f;
constexpr float QSCL  = INV_T * LOG2E;          // fold log2e into Q scale
constexpr float NEG   = -1e30f;
constexpr float DEFER = 8.0f;                   // defer-rescale threshold (log2 units)

__device__ __forceinline__ unsigned short f2b(float x) {
    union { float f; unsigned u; } c; c.f = x;
    unsigned r = c.u + 0x7FFFu + ((c.u >> 16) & 1u);
    return (unsigned short)(r >> 16);
}

// HW packed fp32->bf16 convert (1 VALU op vs ~7 for manual round-ne)
__device__ __forceinline__ unsigned cvtpk(float lo, float hi) {
    unsigned r;
    asm("v_cvt_pk_bf16_f32 %0, %1, %2" : "=v"(r) : "v"(lo), "v"(hi));
    return r;
}

__device__ __forceinline__ short4v mk4(unsigned lo, unsigned hi) {
    union { unsigned u[2]; short4v s; } x; x.u[0] = lo; x.u[1] = hi; return x.s;
}

// 16x16x16 bf16 MFMA: B-frag layout B[k=4*l4+j][col=l15] == native S^T C-layout,
// so P feeds PV straight from registers (no cross-lane movement).
__device__ __forceinline__ f32x4 mfma16(short4v a, short4v b, f32x4 c) {
#if __has_builtin(__builtin_amdgcn_mfma_f32_16x16x16bf16_1k)
    return __builtin_amdgcn_mfma_f32_16x16x16bf16_1k(a, b, c, 0, 0, 0);
#else
    f32x4 d;
    asm("v_mfma_f32_16x16x16_bf16 %0, %1, %2, %3"
        : "=v"(d) : "v"(a), "v"(b), "0"(c));
    return d;
#endif
}

__device__ __forceinline__ void gload_lds16(const void* g, void* l) {
    __builtin_amdgcn_global_load_lds(
        (const __attribute__((address_space(1))) unsigned int*)g,
        (__attribute__((address_space(3))) unsigned int*)l, 16, 0, 0);
}

// ---------------- prepass: K fp32 -> bf16 [bh][s][d] ----------------
__global__ __launch_bounds__(256)
void prep_k(const float* __restrict__ K, unsigned short* __restrict__ Kb) {
    size_t i = ((size_t)blockIdx.x * 256 + threadIdx.x) * 8;
    float4 a = *(const float4*)(K + i);
    float4 b = *(const float4*)(K + i + 4);
    ushort8_t o;
    o[0]=f2b(a.x); o[1]=f2b(a.y); o[2]=f2b(a.z); o[3]=f2b(a.w);
    o[4]=f2b(b.x); o[5]=f2b(b.y); o[6]=f2b(b.z); o[7]=f2b(b.w);
    *(ushort8_t*)(Kb + i) = o;
}

// ---------------- prepass: V fp32 [s][d] -> bf16 V^T [bh][d][s] ----------------
__global__ __launch_bounds__(256)
void prep_v(const float* __restrict__ V, unsigned short* __restrict__ Vt) {
    __shared__ unsigned short T[64][72];
    const int bid = blockIdx.x;
    const int dt = bid & 1, st = (bid >> 1) & 31, bh = bid >> 6;
    const int s0 = st * 64, d0 = dt * 64;
    const float* vb = V + (size_t)bh * SEQ * DH;
    const int tid = threadIdx.x;
    #pragma unroll
    for (int u = 0; u < 4; ++u) {
        int f = tid + 256 * u;
        int sl = f >> 4, c4 = f & 15;
        float4 x = *(const float4*)(vb + (size_t)(s0 + sl) * DH + d0 + c4 * 4);
        T[c4*4+0][sl] = f2b(x.x); T[c4*4+1][sl] = f2b(x.y);
        T[c4*4+2][sl] = f2b(x.z); T[c4*4+3][sl] = f2b(x.w);
    }
    __syncthreads();
    unsigned short* vo = Vt + (size_t)bh * DH * SEQ;
    const int dr = tid >> 2, ch = tid & 3;
    ushort8_t w0 = *(const ushort8_t*)&T[dr][ch*16];
    ushort8_t w1 = *(const ushort8_t*)&T[dr][ch*16 + 8];
    *(ushort8_t*)(vo + (size_t)(d0+dr)*SEQ + s0 + ch*16)     = w0;
    *(ushort8_t*)(vo + (size_t)(d0+dr)*SEQ + s0 + ch*16 + 8) = w1;
}

// ---------------- main: causal flash attention, 32 q-rows per wave ----------------
// Swapped QK^T (S^T = mfma(K,Q)): lane owns 2 q-rows (l15, l15+16), softmax fully
// in-register. Each K/V LDS read feeds both q-halfsets (halves LDS bytes/FLOP).
// PV uses 16x16x16 MFMA so P's native layout IS the B-fragment (no shuffles).
// R6: cvt_pk packing, defer-skipped pmax reduce, masked-f pruning.
__global__ __launch_bounds__(256, 2)
void attn_fwd3(const float* __restrict__ Q,
               const unsigned short* __restrict__ Kb,
               const unsigned short* __restrict__ Vt,
               float* __restrict__ O)
{
    __shared__ __align__(16) unsigned short Ksh[2][64 * 128];
    __shared__ __align__(16) unsigned short Vsh[2][128 * 64];

    const int bid  = blockIdx.x;
    const int qblk = 15 - (bid >> 5);       // descending size: LPT scheduling
    const int bh   = bid & 31;
    const int tid  = threadIdx.x;
    const int wid  = tid >> 6;
    const int lane = tid & 63;
    const int l15  = lane & 15;
    const int l4   = lane >> 4;
    const int rx   = l15 & 7;               // row&7 for all fragment rows (16x+l15)

    const size_t base = (size_t)bh * SEQ * DH;
    const unsigned short* Kbh = Kb + base;        // [s][d]
    const unsigned short* Vth = Vt + base;        // [d][s]

    const int qbase = qblk * 128 + wid * 32;
    const int nt    = 2 * qblk + 2;
    const int qr0   = qbase + l15;
    const int qr1   = qbase + 16 + l15;
    const int qtop  = qbase + 31;           // wave's last q row

    auto stage = [&](int bufi, int tt) {
        const int kv0 = tt * KBLK;
        {   // K: 64 rows x 256B
            const int sl = lane & 15, rr = lane >> 4;
            #pragma unroll
            for (int i = 0; i < 4; ++i) {
                int row = wid * 16 + i * 4 + rr;
                int ss  = sl ^ (row & 7);
                gload_lds16(Kbh + (size_t)(kv0 + row) * DH + ss * 8,
                            &Ksh[bufi][(wid * 16 + i * 4) * 128]);
            }
        }
        {   // V^T: 128 rows x 128B
            const int sl = lane & 7, rr = lane >> 3;
            #pragma unroll
            for (int i = 0; i < 4; ++i) {
                int row = wid * 32 + i * 8 + rr;
                int ss  = sl ^ (row & 7);
                gload_lds16(Vth + (size_t)row * SEQ + kv0 + ss * 8,
                            &Vsh[bufi][(wid * 32 + i * 8) * 64]);
            }
        }
    };

    // ---- Q fragments (B-operand layout) for both q-halfsets, scaled ----
    short8 aq0[4], aq1[4];
    {
        const float* qp0 = Q + base + (size_t)qr0 * DH + 8 * l4;
        const float* qp1 = Q + base + (size_t)qr1 * DH + 8 * l4;
        #pragma unroll
        for (int kb = 0; kb < 4; ++kb) {
            float4 x0 = *(const float4*)(qp0 + 32 * kb);
            float4 x1 = *(const float4*)(qp0 + 32 * kb + 4);
            float4 y0 = *(const float4*)(qp1 + 32 * kb);
            float4 y1 = *(const float4*)(qp1 + 32 * kb + 4);
            short8 a, b;
            a[0] = (short)f2b(x0.x * QSCL); a[1] = (short)f2b(x0.y * QSCL);
            a[2] = (short)f2b(x0.z * QSCL); a[3] = (short)f2b(x0.w * QSCL);
            a[4] = (short)f2b(x1.x * QSCL); a[5] = (short)f2b(x1.y * QSCL);
            a[6] = (short)f2b(x1.z * QSCL); a[7] = (short)f2b(x1.w * QSCL);
            b[0] = (short)f2b(y0.x * QSCL); b[1] = (short)f2b(y0.y * QSCL);
            b[2] = (short)f2b(y0.z * QSCL); b[3] = (short)f2b(y0.w * QSCL);
            b[4] = (short)f2b(y1.x * QSCL); b[5] = (short)f2b(y1.y * QSCL);
            b[6] = (short)f2b(y1.z * QSCL); b[7] = (short)f2b(y1.w * QSCL);
            aq0[kb] = a; aq1[kb] = b;
        }
    }

    f32x4 acc0[8], acc1[8];     // O^T: acc{qs}[db][j] = O[qr{qs}][16db+4l4+j]
    #pragma unroll
    for (int i = 0; i < 8; ++i) {
        acc0[i] = (f32x4){0.f, 0.f, 0.f, 0.f};
        acc1[i] = (f32x4){0.f, 0.f, 0.f, 0.f};
    }
    float mrun0 = NEG, lrun0 = 0.f;
    float mrun1 = NEG, lrun1 = 0.f;

    stage(0, 0);

    for (int t = 0; t < nt; ++t) {
        const int cur = t & 1;
        const int kvb = t * KBLK;
        asm volatile("s_waitcnt vmcnt(0)" ::: "memory");
        __syncthreads();
        if (t + 1 < nt) stage(cur ^ 1, t + 1);

        if (kvb <= qtop) {
            const unsigned short* Kc = Ksh[cur];
            const unsigned short* Vc = Vsh[cur];
            // f-block kv range [kvb+16f, kvb+16f+16): fully masked if kvb+16f > qtop
            const bool fok1 = (kvb + 16 <= qtop);
            const bool fok2 = (kvb + 32 <= qtop);
            const bool fok3 = (kvb + 48 <= qtop);

            // ---- S^T = K · Q^T (64kv x 32q): each K b128 feeds both q-halves ----
            f32x4 sf0[4], sf1[4];
            __builtin_amdgcn_s_setprio(1);
            #pragma unroll
            for (int f = 0; f < 4; ++f) {
                if (f == 1 && !fok1) break;
                if (f == 2 && !fok2) break;
                if (f == 3 && !fok3) break;
                f32x4 c0 = (f32x4){0.f, 0.f, 0.f, 0.f};
                f32x4 c1 = (f32x4){0.f, 0.f, 0.f, 0.f};
                const int row = 16 * f + l15;
                #pragma unroll
                for (int kb = 0; kb < 4; ++kb) {
                    short8 bk = *(const short8*)&Kc[row * 128 + ((4 * kb + l4) ^ rx) * 8];
                    c0 = __builtin_amdgcn_mfma_f32_16x16x32_bf16(bk, aq0[kb], c0, 0, 0, 0);
                    c1 = __builtin_amdgcn_mfma_f32_16x16x32_bf16(bk, aq1[kb], c1, 0, 0, 0);
                }
                sf0[f] = c0; sf1[f] = c1;
            }
            __builtin_amdgcn_s_setprio(0);
            const int nf = fok3 ? 4 : (fok2 ? 3 : (fok1 ? 2 : 1));

            // ---- causal mask (tiles overlapping the wave's diagonal) ----
            if (kvb + KBLK - 1 > qbase) {
                #pragma unroll
                for (int f = 0; f < 4; ++f) {
                    if (f >= nf) break;
                    #pragma unroll
                    for (int j = 0; j < 4; ++j) {
                        const int kv = kvb + 16 * f + 4 * l4 + j;
                        if (kv > qr0) sf0[f][j] = NEG;
                        if (kv > qr1) sf1[f][j] = NEG;
                    }
                }
            }

            // ---- local (per-lane) max only; full reduce deferred ----
            float lm0 = NEG, lm1 = NEG;
            #pragma unroll
            for (int f = 0; f < 4; ++f) {
                if (f >= nf) break;
                lm0 = fmaxf(lm0, fmaxf(fmaxf(sf0[f][0], sf0[f][1]),
                                       fmaxf(sf0[f][2], sf0[f][3])));
                lm1 = fmaxf(lm1, fmaxf(fmaxf(sf1[f][0], sf1[f][1]),
                                       fmaxf(sf1[f][2], sf1[f][3])));
            }

            // ---- defer-rescale (T13): reduce + rescale only when max grew ----
            if (__any((lm0 > mrun0 + DEFER) || (lm1 > mrun1 + DEFER))) {
                float pm0 = fmaxf(lm0, __shfl_xor(lm0, 16));
                pm0 = fmaxf(pm0, __shfl_xor(pm0, 32));
                float pm1 = fmaxf(lm1, __shfl_xor(lm1, 16));
                pm1 = fmaxf(pm1, __shfl_xor(pm1, 32));
                float mn0 = fmaxf(mrun0, pm0), mn1 = fmaxf(mrun1, pm1);
                float s0 = exp2f(mrun0 - mn0), s1 = exp2f(mrun1 - mn1);
                mrun0 = mn0; mrun1 = mn1;
                lrun0 *= s0; lrun1 *= s1;
                #pragma unroll
                for (int i = 0; i < 8; ++i)
                    #pragma unroll
                    for (int j = 0; j < 4; ++j) {
                        acc0[i][j] *= s0;
                        acc1[i][j] *= s1;
                    }
            }

            // ---- P = exp2(S - m), row sums, HW-packed bf16 dword pairs ----
            unsigned pa0[4], pb0_[4], pa1[4], pb1_[4];
            float rs0 = 0.f, rs1 = 0.f;
            #pragma unroll
            for (int f = 0; f < 4; ++f) {
                if (f >= nf) break;
                float p00 = exp2f(sf0[f][0] - mrun0), p01 = exp2f(sf0[f][1] - mrun0);
                float p02 = exp2f(sf0[f][2] - mrun0), p03 = exp2f(sf0[f][3] - mrun0);
                float p10 = exp2f(sf1[f][0] - mrun1), p11 = exp2f(sf1[f][1] - mrun1);
                float p12 = exp2f(sf1[f][2] - mrun1), p13 = exp2f(sf1[f][3] - mrun1);
                rs0 += (p00 + p01) + (p02 + p03);
                rs1 += (p10 + p11) + (p12 + p13);
                pa0[f]  = cvtpk(p00, p01); pb0_[f] = cvtpk(p02, p03);
                pa1[f]  = cvtpk(p10, p11); pb1_[f] = cvtpk(p12, p13);
            }
            rs0 += __shfl_xor(rs0, 16); rs0 += __shfl_xor(rs0, 32);
            rs1 += __shfl_xor(rs1, 16); rs1 += __shfl_xor(rs1, 32);
            lrun0 += rs0; lrun1 += rs1;

            // ---- PV: O^T += V^T · P via 16x16x16 (P native layout = B-frag) ----
            #pragma unroll
            for (int f = 0; f < 4; ++f) {
                if (f >= nf) break;
                short4v pf0 = mk4(pa0[f], pb0_[f]);
                short4v pf1 = mk4(pa1[f], pb1_[f]);
                __builtin_amdgcn_s_setprio(1);
                #pragma unroll
                for (int db = 0; db < 8; ++db) {
                    const int row = 16 * db + l15;
                    short4v va = *(const short4v*)
                        &Vc[row * 64 + ((2 * f + (l4 >> 1)) ^ rx) * 8 + (l4 & 1) * 4];
                    acc0[db] = mfma16(va, pf0, acc0[db]);
                    acc1[db] = mfma16(va, pf1, acc1[db]);
                }
                __builtin_amdgcn_s_setprio(0);
            }
        }
    }

    // ---- epilogue: O[qr][16db+4l4+j] = acc/l, float4 stores ----
    const float inv0 = 1.f / lrun0;
    const float inv1 = 1.f / lrun1;
    float* op0 = O + base + (size_t)qr0 * DH + 4 * l4;
    float* op1 = O + base + (size_t)qr1 * DH + 4 * l4;
    #pragma unroll
    for (int db = 0; db < 8; ++db) {
        float4 v0, v1;
        v0.x = acc0[db][0] * inv0; v0.y = acc0[db][1] * inv0;
        v0.z = acc0[db][2] * inv0; v0.w = acc0[db][3] * inv0;
        v1.x = acc1[db][0] * inv1; v1.y = acc1[db][1] * inv1;
        v1.z = acc1[db][2] * inv1; v1.w = acc1[db][3] * inv1;
        *(float4*)(op0 + 16 * db) = v0;
        *(float4*)(op1 + 16 * db) = v1;
    }
}

// ---------------- legacy fallback (round-1 kernel, used if ws too small) ----------------
__global__ __launch_bounds__(256)
void attn_fwd(const float* __restrict__ Q, const float* __restrict__ K,
              const float* __restrict__ V, float* __restrict__ O)
{
    __shared__ __align__(16) unsigned short KshL[KBLK * KS];
    __shared__ __align__(16) unsigned short VshL[DH * VS];
    __shared__ __align__(16) unsigned short PshL[4][QW * PS];

    const int bid  = blockIdx.x;
    const int qblk = bid & 31;
    const int bh   = bid >> 5;
    const int tid  = threadIdx.x;
    const int wid  = tid >> 6;
    const int lane = tid & 63;
    const int l15  = lane & 15;
    const int l4   = lane >> 4;

    const size_t base  = (size_t)bh * SEQ * DH;
    const int    qbase = qblk * QB + wid * QW;

    short8 aq[4];
    {
        const float* qp = Q + base + (size_t)(qbase + l15) * DH + 8 * l4;
        #pragma unroll
        for (int kb = 0; kb < 4; ++kb) {
            float4 x0 = *(const float4*)(qp + 32 * kb);
            float4 x1 = *(const float4*)(qp + 32 * kb + 4);
            short8 a;
            a[0] = (short)f2b(x0.x * INV_T); a[1] = (short)f2b(x0.y * INV_T);
            a[2] = (short)f2b(x0.z * INV_T); a[3] = (short)f2b(x0.w * INV_T);
            a[4] = (short)f2b(x1.x * INV_T); a[5] = (short)f2b(x1.y * INV_T);
            a[6] = (short)f2b(x1.z * INV_T); a[7] = (short)f2b(x1.w * INV_T);
            aq[kb] = a;
        }
    }
    f32x4 acc[8];
    #pragma unroll
    for (int i = 0; i < 8; ++i) acc[i] = (f32x4){0.f, 0.f, 0.f, 0.f};
    float mrun[4], lrun[4];
    #pragma unroll
    for (int j = 0; j < 4; ++j) { mrun[j] = NEG; lrun[j] = 0.f; }

    const int ntiles = qblk + 1;
    for (int t = 0; t < ntiles; ++t) {
        const int kvb = t * KBLK;
        #pragma unroll
        for (int i = 0; i < 8; ++i) {
            int f  = tid + 256 * i;
            int kv = f >> 5, c4 = f & 31;
            float4 x = *(const float4*)(K + base + (size_t)(kvb + kv) * DH + 4 * c4);
            ushort4 b4;
            b4.x = f2b(x.x); b4.y = f2b(x.y); b4.z = f2b(x.z); b4.w = f2b(x.w);
            *(ushort4*)&KshL[kv * KS + 4 * c4] = b4;
        }
        {
            const int dd  = tid & 127;
            const int kvg = (tid >> 7) * 8;
            #pragma unroll
            for (int p = 0; p < 4; ++p) {
                const int kvL = p * 16 + kvg;
                const float* vp = V + base + (size_t)(kvb + kvL) * DH + dd;
                float x[8];
                #pragma unroll
                for (int j = 0; j < 8; ++j) x[j] = vp[(size_t)j * DH];
                ushort4 lo, hi;
                lo.x = f2b(x[0]); lo.y = f2b(x[1]); lo.z = f2b(x[2]); lo.w = f2b(x[3]);
                hi.x = f2b(x[4]); hi.y = f2b(x[5]); hi.z = f2b(x[6]); hi.w = f2b(x[7]);
                *(ushort4*)&VshL[dd * VS + kvL]     = lo;
                *(ushort4*)&VshL[dd * VS + kvL + 4] = hi;
            }
        }
        __syncthreads();
        if (kvb <= qbase + QW - 1) {
            f32x4 sf[4];
            #pragma unroll
            for (int f = 0; f < 4; ++f) {
                f32x4 c = (f32x4){0.f, 0.f, 0.f, 0.f};
                #pragma unroll
                for (int kb = 0; kb < 4; ++kb) {
                    short8 bk = *(const short8*)&KshL[(16 * f + l15) * KS + 32 * kb + 8 * l4];
                    c = __builtin_amdgcn_mfma_f32_16x16x32_bf16(aq[kb], bk, c, 0, 0, 0);
                }
                sf[f] = c;
            }
            float pmax[4] = {NEG, NEG, NEG, NEG};
            #pragma unroll
            for (int f = 0; f < 4; ++f) {
                const int col = kvb + 16 * f + l15;
                #pragma unroll
                for (int j = 0; j < 4; ++j) {
                    const int row = qbase + 4 * l4 + j;
                    float val = (col <= row) ? sf[f][j] : NEG;
                    sf[f][j] = val;
                    pmax[j] = fmaxf(pmax[j], val);
                }
            }
            #pragma unroll
            for (int j = 0; j < 4; ++j) {
                #pragma unroll
                for (int off = 8; off > 0; off >>= 1)
                    pmax[j] = fmaxf(pmax[j], __shfl_xor(pmax[j], off));
            }
            float scl[4], rsum[4];
            #pragma unroll
            for (int j = 0; j < 4; ++j) {
                float mn = fmaxf(mrun[j], pmax[j]);
                scl[j]  = exp2f((mrun[j] - mn) * LOG2E);
                mrun[j] = mn;
                rsum[j] = 0.f;
            }
            #pragma unroll
            for (int f = 0; f < 4; ++f) {
                #pragma unroll
                for (int j = 0; j < 4; ++j) {
                    float pv = exp2f((sf[f][j] - mrun[j]) * LOG2E);
                    sf[f][j] = pv;
                    rsum[j] += pv;
                }
            }
            #pragma unroll
            for (int j = 0; j < 4; ++j) {
                #pragma unroll
                for (int off = 8; off > 0; off >>= 1)
                    rsum[j] += __shfl_xor(rsum[j], off);
                lrun[j] = lrun[j] * scl[j] + rsum[j];
            }
            #pragma unroll
            for (int i = 0; i < 8; ++i)
                #pragma unroll
                for (int j = 0; j < 4; ++j)
                    acc[i][j] *= scl[j];
            #pragma unroll
            for (int f = 0; f < 4; ++f)
                #pragma unroll
                for (int j = 0; j < 4; ++j)
                    PshL[wid][(4 * l4 + j) * PS + 16 * f + l15] = f2b(sf[f][j]);
            #pragma unroll
            for (int kb = 0; kb < 2; ++kb) {
                short8 pa = *(const short8*)&PshL[wid][l15 * PS + 32 * kb + 8 * l4];
                #pragma unroll
                for (int db = 0; db < 8; ++db) {
                    short8 bv = *(const short8*)&VshL[(16 * db + l15) * VS + 32 * kb + 8 * l4];
                    acc[db] = __builtin_amdgcn_mfma_f32_16x16x32_bf16(pa, bv, acc[db], 0, 0, 0);
                }
            }
        }
        __syncthreads();
    }
    float inv[4];
    #pragma unroll
    for (int j = 0; j < 4; ++j) inv[j] = 1.f / lrun[j];
    float* op = O + base + (size_t)qbase * DH;
    #pragma unroll
    for (int db = 0; db < 8; ++db)
        #pragma unroll
        for (int j = 0; j < 4; ++j)
            op[(size_t)(4 * l4 + j) * DH + 16 * db + l15] = acc[db][j] * inv[j];
}

extern "C" void kernel_launch(void* const* d_in, const int* in_sizes, int n_in,
                              void* d_out, int out_size, void* d_ws, size_t ws_size,
                              hipStream_t stream) {
    const float* q = (const float*)d_in[0];
    const float* k = (const float*)d_in[1];
    const float* v = (const float*)d_in[2];
    float* o = (float*)d_out;

    const size_t elems = (size_t)NBH * SEQ * DH;
    const size_t need  = elems * 2 * sizeof(unsigned short);   // Kbf + Vt, 33.5 MB
    if (ws_size >= need) {
        unsigned short* Kb = (unsigned short*)d_ws;
        unsigned short* Vt = Kb + elems;
        prep_k<<<dim3((unsigned)(elems / (256 * 8))), dim3(256), 0, stream>>>(k, Kb);
        prep_v<<<dim3(NBH * (SEQ / 64) * (DH / 64)), dim3(256), 0, stream>>>(v, Vt);
        attn_fwd3<<<dim3(NBH * 16), dim3(256), 0, stream>>>(q, Kb, Vt, o);
    } else {
        attn_fwd<<<dim3(NBH * 32), dim3(256), 0, stream>>>(q, k, v, o);
    }
}